// Round 3
// baseline (86562.500 us; speedup 1.0000x reference)
//
#include <hip/hip_runtime.h>
#include <hip/hip_bf16.h>

// ---------------- parameters (all inputs fp32; output fp32) ----------------
struct P19 {
  const float *src;
  const float *eWih0, *eWhh0, *ebih0, *ebhh0;
  const float *eWih1, *eWhh1, *ebih1, *ebhh1;
  const float *dWih0, *dWhh0, *dbih0, *dbhh0;
  const float *dWih1, *dWhh1, *dbih1, *dbhh1;
  const float *fcW, *fcb;
  float *out;
  float *ws;
};

__device__ __forceinline__ float sigf(float x) {
  return 1.f / (1.f + __expf(-x));
}

// two-phase device-scope grid barrier; all 256 blocks resident (96KB LDS ->
// 1 block/CU, grid == CU count). Guarded spin: cannot hang the harness.
__device__ __forceinline__ void gridbar(unsigned *cnt, unsigned *gen) {
  __syncthreads();
  if (threadIdx.x == 0) {
    __threadfence();  // release: make our h writes visible across XCDs
    unsigned g = __hip_atomic_load(gen, __ATOMIC_RELAXED, __HIP_MEMORY_SCOPE_AGENT);
    unsigned a = __hip_atomic_fetch_add(cnt, 1u, __ATOMIC_ACQ_REL, __HIP_MEMORY_SCOPE_AGENT);
    if (a == 255u) {
      __hip_atomic_store(cnt, 0u, __ATOMIC_RELAXED, __HIP_MEMORY_SCOPE_AGENT);
      __hip_atomic_fetch_add(gen, 1u, __ATOMIC_ACQ_REL, __HIP_MEMORY_SCOPE_AGENT);
    } else {
      int guard = 0;
      while (__hip_atomic_load(gen, __ATOMIC_ACQUIRE, __HIP_MEMORY_SCOPE_AGENT) == g) {
        __builtin_amdgcn_s_sleep(2);
        if (++guard > (1 << 16)) break;  // safety: never deadlock the bench
      }
    }
    __threadfence();  // acquire: invalidate L1/L2 before reading others' h
  }
  __syncthreads();
}

// acc(4 gates) += W[k][gate] (LDS, lane-uniform broadcast read) * h[k]
// (global, transposed layout [k][b] -> lane-consecutive coalesced loads)
__device__ __forceinline__ void dot512(float4 &acc, const float *__restrict__ w,
                                       const float *__restrict__ hcol) {
#pragma unroll 8
  for (int k = 0; k < 512; ++k) {
    float hk = hcol[k * 128];
    float4 wv = *(const float4 *)(w + 4 * k);
    acc.x = fmaf(wv.x, hk, acc.x);
    acc.y = fmaf(wv.y, hk, acc.y);
    acc.z = fmaf(wv.z, hk, acc.z);
    acc.w = fmaf(wv.w, hk, acc.w);
  }
}

__global__ __launch_bounds__(256, 1) void seq2seq_kernel(P19 p) {
  const int tid = threadIdx.x;
  const int blk = blockIdx.x;
  const int b = tid & 127;     // batch
  const int ul = tid >> 7;     // unit-local (0..1)
  const int u = blk * 2 + ul;  // hidden unit 0..511

  float *ws = p.ws;
  unsigned *cnt = (unsigned *)ws;
  unsigned *gen = (unsigned *)ws + 1;
  float *h0buf[2] = {ws + 64, ws + 64 + 65536};            // [unit][b], parity
  float *h1buf[2] = {ws + 64 + 131072, ws + 64 + 196608};  // [unit][b], parity
  float *outp = ws + 64 + 262144;                          // [j][b] : 6*128

  // LDS: 6 matrices x 2 units x 512 k x 4 gates, fp32 = 96 KiB
  __shared__ __align__(16) float wl[24576];

  {  // ---- stage big-weight slices into LDS (once, reused 1000+ rounds) ----
    const float *mats[6] = {p.eWhh0, p.eWih1, p.eWhh1, p.dWhh0, p.dWih1, p.dWhh1};
    for (int m = 0; m < 6; ++m)
      for (int uu = 0; uu < 2; ++uu) {
        int unit = blk * 2 + uu;
        for (int g = 0; g < 4; ++g) {
          const float *row = mats[m] + (size_t)(g * 512 + unit) * 512;
          float *dst = wl + (m * 2 + uu) * 2048 + g;
          for (int k = tid; k < 512; k += 256) dst[k * 4] = row[k];
        }
      }
  }

  // ---- per-thread small weights & fused biases (registers) ----
  float wx0e[24], wx0d[24], be0[4], be1[4], bd0[4], bd1[4];
#pragma unroll
  for (int g = 0; g < 4; ++g) {
    int r = g * 512 + u;
#pragma unroll
    for (int i = 0; i < 6; ++i) {
      wx0e[g * 6 + i] = p.eWih0[r * 6 + i];
      wx0d[g * 6 + i] = p.dWih0[r * 6 + i];
    }
    be0[g] = p.ebih0[r] + p.ebhh0[r];
    be1[g] = p.ebih1[r] + p.ebhh1[r];
    bd0[g] = p.dbih0[r] + p.dbhh0[r];
    bd1[g] = p.dbih1[r] + p.dbhh1[r];
  }

  // ---- init: seed decoder input = src[:,255,:] (transposed [j][b]) ----
  {
    int g0 = blk * 256 + tid;
    if (g0 < 768) {
      int bb = g0 & 127, i = g0 >> 7;
      outp[i * 128 + bb] = p.src[((size_t)bb * 256 + 255) * 6 + i];
    }
  }
  float c0 = 0.f, c1 = 0.f;  // cell states live in registers forever

  gridbar(cnt, gen);

  // ================= encoder: layer0 & layer1 pipelined (lag 1) ============
  for (int t = 0; t <= 256; ++t) {
    if (t < 256) {  // enc layer0, step t
      float4 a = make_float4(be0[0], be0[1], be0[2], be0[3]);
      const float *xr = p.src + ((size_t)b * 256 + t) * 6;
#pragma unroll
      for (int i = 0; i < 6; ++i) {
        float xv = xr[i];
        a.x = fmaf(wx0e[i], xv, a.x);
        a.y = fmaf(wx0e[6 + i], xv, a.y);
        a.z = fmaf(wx0e[12 + i], xv, a.z);
        a.w = fmaf(wx0e[18 + i], xv, a.w);
      }
      dot512(a, wl + (0 * 2 + ul) * 2048, h0buf[t & 1] + b);
      float ig = sigf(a.x), fg = sigf(a.y);
      float gg = tanhf(a.z), og = sigf(a.w);
      c0 = fg * c0 + ig * gg;
      h0buf[(t + 1) & 1][u * 128 + b] = og * tanhf(c0);
    }
    if (t >= 1) {  // enc layer1, step t-1 (its input y0[t-1] == h0buf[t&1])
      int s1 = t - 1;
      float4 a = make_float4(be1[0], be1[1], be1[2], be1[3]);
      dot512(a, wl + (1 * 2 + ul) * 2048, h0buf[t & 1] + b);
      dot512(a, wl + (2 * 2 + ul) * 2048, h1buf[s1 & 1] + b);
      float ig = sigf(a.x), fg = sigf(a.y);
      float gg = tanhf(a.z), og = sigf(a.w);
      c1 = fg * c1 + ig * gg;
      h1buf[(s1 + 1) & 1][u * 128 + b] = og * tanhf(c1);
    }
    gridbar(cnt, gen);
  }
  // final enc states: h0 in h0buf[0], h1 in h1buf[0]; c0,c1 in registers.

  // ================= decoder: 3 rounds per step ============================
  for (int s = 0; s < 256; ++s) {
    {  // R_A: dec layer0 (input = previous fc output, 6-dim)
      float4 a = make_float4(bd0[0], bd0[1], bd0[2], bd0[3]);
#pragma unroll
      for (int i = 0; i < 6; ++i) {
        float xv = outp[i * 128 + b];
        a.x = fmaf(wx0d[i], xv, a.x);
        a.y = fmaf(wx0d[6 + i], xv, a.y);
        a.z = fmaf(wx0d[12 + i], xv, a.z);
        a.w = fmaf(wx0d[18 + i], xv, a.w);
      }
      dot512(a, wl + (3 * 2 + ul) * 2048, h0buf[s & 1] + b);
      float ig = sigf(a.x), fg = sigf(a.y);
      float gg = tanhf(a.z), og = sigf(a.w);
      c0 = fg * c0 + ig * gg;
      h0buf[(s + 1) & 1][u * 128 + b] = og * tanhf(c0);
    }
    gridbar(cnt, gen);
    {  // R_B: dec layer1 (inputs: dh0[s] just written, dh1[s-1])
      float4 a = make_float4(bd1[0], bd1[1], bd1[2], bd1[3]);
      dot512(a, wl + (4 * 2 + ul) * 2048, h0buf[(s + 1) & 1] + b);
      dot512(a, wl + (5 * 2 + ul) * 2048, h1buf[s & 1] + b);
      float ig = sigf(a.x), fg = sigf(a.y);
      float gg = tanhf(a.z), og = sigf(a.w);
      c1 = fg * c1 + ig * gg;
      h1buf[(s + 1) & 1][u * 128 + b] = og * tanhf(c1);
    }
    gridbar(cnt, gen);
    {  // R_C: fc head -> next decoder input + final output (768 lanes)
      int g0 = blk * 256 + tid;
      if (g0 < 768) {
        int bb = g0 & 127, j = g0 >> 7;
        float acc = p.fcb[j];
        const float *wr = p.fcW + j * 512;
        const float *hc = h1buf[(s + 1) & 1] + bb;
#pragma unroll 8
        for (int k = 0; k < 512; ++k)
          acc = fmaf(wr[k], hc[k * 128], acc);
        outp[j * 128 + bb] = acc;
        p.out[((size_t)bb * 256 + s) * 6 + j] = acc;  // fp32 output
      }
    }
    gridbar(cnt, gen);
  }
}

extern "C" void kernel_launch(void *const *d_in, const int *in_sizes, int n_in,
                              void *d_out, int out_size, void *d_ws, size_t ws_size,
                              hipStream_t stream) {
  (void)in_sizes; (void)n_in; (void)out_size; (void)ws_size;
  P19 p;
  p.src = (const float *)d_in[0];
  p.eWih0 = (const float *)d_in[1];  p.eWhh0 = (const float *)d_in[2];
  p.ebih0 = (const float *)d_in[3];  p.ebhh0 = (const float *)d_in[4];
  p.eWih1 = (const float *)d_in[5];  p.eWhh1 = (const float *)d_in[6];
  p.ebih1 = (const float *)d_in[7];  p.ebhh1 = (const float *)d_in[8];
  p.dWih0 = (const float *)d_in[9];  p.dWhh0 = (const float *)d_in[10];
  p.dbih0 = (const float *)d_in[11]; p.dbhh0 = (const float *)d_in[12];
  p.dWih1 = (const float *)d_in[13]; p.dWhh1 = (const float *)d_in[14];
  p.dbih1 = (const float *)d_in[15]; p.dbhh1 = (const float *)d_in[16];
  p.fcW = (const float *)d_in[17];   p.fcb = (const float *)d_in[18];
  p.out = (float *)d_out;
  p.ws = (float *)d_ws;

  // zero barrier words + h0/h1 parity buffers (outp is written by the kernel
  // before first use). Graph-capture-legal.
  hipMemsetAsync(d_ws, 0, (size_t)(64 + 4 * 65536) * sizeof(float), stream);
  seq2seq_kernel<<<dim3(256), dim3(256), 0, stream>>>(p);
}

// Round 4
// 43381.015 us; speedup vs baseline: 1.9954x; 1.9954x over previous
//
#include <hip/hip_runtime.h>
#include <hip/hip_fp16.h>

// ---------------- parameters (all inputs fp32; output fp32) ----------------
struct P19 {
  const float *src;
  const float *eWih0, *eWhh0, *ebih0, *ebhh0;
  const float *eWih1, *eWhh1, *ebih1, *ebhh1;
  const float *dWih0, *dWhh0, *dbih0, *dbhh0;
  const float *dWih1, *dWhh1, *dbih1, *dbhh1;
  const float *fcW, *fcb;
  float *out;
  float *ws;
};

__device__ __forceinline__ float sigf(float x) {
  return 1.f / (1.f + __expf(-x));
}

// pack two fp32 h-values (units 2k2, 2k2+1) into one dword of 2x fp16 (RTNE)
__device__ __forceinline__ unsigned packh(float a, float b2) {
  __half2 h2 = __floats2half2_rn(a, b2);
  return *(const unsigned *)&h2;
}

// two-phase device-scope grid barrier (proven in round 3); all 256 blocks
// resident (98.5KB LDS -> 1 block/CU, grid == CU count). Guarded spin.
__device__ __forceinline__ void gridbar(unsigned *cnt, unsigned *gen) {
  __syncthreads();
  if (threadIdx.x == 0) {
    __threadfence();  // release: h writes visible across XCDs
    unsigned g = __hip_atomic_load(gen, __ATOMIC_RELAXED, __HIP_MEMORY_SCOPE_AGENT);
    unsigned a = __hip_atomic_fetch_add(cnt, 1u, __ATOMIC_ACQ_REL, __HIP_MEMORY_SCOPE_AGENT);
    if (a == 255u) {
      __hip_atomic_store(cnt, 0u, __ATOMIC_RELAXED, __HIP_MEMORY_SCOPE_AGENT);
      __hip_atomic_fetch_add(gen, 1u, __ATOMIC_ACQ_REL, __HIP_MEMORY_SCOPE_AGENT);
    } else {
      int guard = 0;
      while (__hip_atomic_load(gen, __ATOMIC_ACQUIRE, __HIP_MEMORY_SCOPE_AGENT) == g) {
        __builtin_amdgcn_s_sleep(2);
        if (++guard > (1 << 16)) break;  // safety: never deadlock the bench
      }
    }
    __threadfence();  // acquire: invalidate caches before reading others' h
  }
  __syncthreads();
}

// ---- pipelined dots over packed-fp16 h (256 dwords = 512 k) ----
// w layout per k2: 8 floats = [4 gates @ k=2k2][4 gates @ k=2k2+1]
#define DBODY(ACC, WP)                                              \
  {                                                                 \
    const float4 *W = (const float4 *)((WP) + k2 * 8);              \
    float4 we = W[0], wo = W[1];                                    \
    ACC.x = fmaf(we.x, hf.x, ACC.x); ACC.y = fmaf(we.y, hf.x, ACC.y); \
    ACC.z = fmaf(we.z, hf.x, ACC.z); ACC.w = fmaf(we.w, hf.x, ACC.w); \
    ACC.x = fmaf(wo.x, hf.y, ACC.x); ACC.y = fmaf(wo.y, hf.y, ACC.y); \
    ACC.z = fmaf(wo.z, hf.y, ACC.z); ACC.w = fmaf(wo.w, hf.y, ACC.w); \
  }

__device__ __forceinline__ void dot_one(float4 &A0, const float *__restrict__ w0,
                                        const unsigned *__restrict__ hp) {
  unsigned bufa[32], bufb[32];
#pragma unroll
  for (int c = 0; c < 32; ++c) bufa[c] = hp[c * 128];
  for (int j = 0; j < 8; j += 2) {
    int jn = j + 1, jn2 = (j + 2) & 7;  // wrap: redundant chunk-0 reload, harmless
#pragma unroll
    for (int c = 0; c < 32; ++c) bufb[c] = hp[(jn * 32 + c) * 128];
#pragma unroll
    for (int c = 0; c < 32; ++c) {
      int k2 = j * 32 + c;
      unsigned d = bufa[c];
      float2 hf = __half22float2(*(const __half2 *)&d);
      DBODY(A0, w0)
    }
#pragma unroll
    for (int c = 0; c < 32; ++c) bufa[c] = hp[(jn2 * 32 + c) * 128];
#pragma unroll
    for (int c = 0; c < 32; ++c) {
      int k2 = jn * 32 + c;
      unsigned d = bufb[c];
      float2 hf = __half22float2(*(const __half2 *)&d);
      DBODY(A0, w0)
    }
  }
}

// shared h loads feeding two weight sets (enc layer0 + layer1 read same h0)
__device__ __forceinline__ void dot_two(float4 &A0, float4 &A1,
                                        const float *__restrict__ w0,
                                        const float *__restrict__ w1,
                                        const unsigned *__restrict__ hp) {
  unsigned bufa[32], bufb[32];
#pragma unroll
  for (int c = 0; c < 32; ++c) bufa[c] = hp[c * 128];
  for (int j = 0; j < 8; j += 2) {
    int jn = j + 1, jn2 = (j + 2) & 7;
#pragma unroll
    for (int c = 0; c < 32; ++c) bufb[c] = hp[(jn * 32 + c) * 128];
#pragma unroll
    for (int c = 0; c < 32; ++c) {
      int k2 = j * 32 + c;
      unsigned d = bufa[c];
      float2 hf = __half22float2(*(const __half2 *)&d);
      DBODY(A0, w0)
      DBODY(A1, w1)
    }
#pragma unroll
    for (int c = 0; c < 32; ++c) bufa[c] = hp[(jn2 * 32 + c) * 128];
#pragma unroll
    for (int c = 0; c < 32; ++c) {
      int k2 = jn * 32 + c;
      unsigned d = bufb[c];
      float2 hf = __half22float2(*(const __half2 *)&d);
      DBODY(A0, w0)
      DBODY(A1, w1)
    }
  }
}

__global__ __launch_bounds__(256, 1) void seq2seq_kernel(P19 p) {
  const int tid = threadIdx.x;
  const int blk = blockIdx.x;
  const int b = tid & 127;     // batch
  const int ul = tid >> 7;     // unit-local (0..1)
  const int u = blk * 2 + ul;  // hidden unit 0..511

  float *ws = p.ws;
  unsigned *cnt = (unsigned *)ws;
  unsigned *gen = (unsigned *)ws + 1;
  // packed fp16 h buffers: [k2][b] dwords, k2 = unit-pair 0..255
  unsigned *hp0[2] = {(unsigned *)(ws + 64), (unsigned *)(ws + 64 + 32768)};
  unsigned *hp1[2] = {(unsigned *)(ws + 64 + 65536), (unsigned *)(ws + 64 + 98304)};
  float *outp = ws + 64 + 131072;  // decoder input [j][b] : 6*128 fp32

  // LDS: 6 matrices x 2 units x 512 k x 4 gates fp32 = 96 KiB (+2KB exchange)
  __shared__ __align__(16) float wl[24576];
  __shared__ float hx[4][128];

  {  // ---- stage big-weight slices into LDS (once) ----
    const float *mats[6] = {p.eWhh0, p.eWih1, p.eWhh1, p.dWhh0, p.dWih1, p.dWhh1};
    for (int m = 0; m < 6; ++m)
      for (int uu = 0; uu < 2; ++uu) {
        int unit = blk * 2 + uu;
        for (int g = 0; g < 4; ++g) {
          const float *row = mats[m] + (size_t)(g * 512 + unit) * 512;
          float *dst = wl + (m * 2 + uu) * 2048 + g;
          for (int k = tid; k < 512; k += 256) dst[k * 4] = row[k];
        }
      }
  }

  // ---- per-thread small weights & fused biases (registers) ----
  float wx0e[24], wx0d[24], be0[4], be1[4], bd0[4], bd1[4];
#pragma unroll
  for (int g = 0; g < 4; ++g) {
    int r = g * 512 + u;
#pragma unroll
    for (int i = 0; i < 6; ++i) {
      wx0e[g * 6 + i] = p.eWih0[r * 6 + i];
      wx0d[g * 6 + i] = p.dWih0[r * 6 + i];
    }
    be0[g] = p.ebih0[r] + p.ebhh0[r];
    be1[g] = p.ebih1[r] + p.ebhh1[r];
    bd0[g] = p.dbih0[r] + p.dbhh0[r];
    bd1[g] = p.dbih1[r] + p.dbhh1[r];
  }

  // ---- init: seed decoder input = src[:,255,:] ----
  {
    int g0 = blk * 256 + tid;
    if (g0 < 768) {
      int bb = g0 & 127, i = g0 >> 7;
      outp[i * 128 + bb] = p.src[((size_t)bb * 256 + 255) * 6 + i];
    }
  }
  float c0 = 0.f, c1 = 0.f;  // cell states live in registers forever

  gridbar(cnt, gen);

  // ================= encoder: layer0 & layer1 pipelined (lag 1) ============
  for (int t = 0; t <= 256; ++t) {
    float4 a0 = make_float4(be0[0], be0[1], be0[2], be0[3]);
    float4 a1 = make_float4(be1[0], be1[1], be1[2], be1[3]);
    float xv[6];
    if (t < 256) {
      const float *xr = p.src + ((size_t)b * 256 + t) * 6;
#pragma unroll
      for (int i = 0; i < 6; ++i) xv[i] = xr[i];
    }
    const unsigned *hpA = hp0[t & 1] + b;
    if (t == 0) {
      dot_one(a0, wl + (0 * 2 + ul) * 2048, hpA);
    } else if (t < 256) {
      dot_two(a0, a1, wl + (0 * 2 + ul) * 2048, wl + (1 * 2 + ul) * 2048, hpA);
    } else {
      dot_one(a1, wl + (1 * 2 + ul) * 2048, hpA);
    }
    if (t >= 1) dot_one(a1, wl + (2 * 2 + ul) * 2048, hp1[(t + 1) & 1] + b);

    if (t < 256) {  // layer0 activation
#pragma unroll
      for (int i = 0; i < 6; ++i) {
        a0.x = fmaf(wx0e[i], xv[i], a0.x);
        a0.y = fmaf(wx0e[6 + i], xv[i], a0.y);
        a0.z = fmaf(wx0e[12 + i], xv[i], a0.z);
        a0.w = fmaf(wx0e[18 + i], xv[i], a0.w);
      }
      float ig = sigf(a0.x), fg = sigf(a0.y), gg = tanhf(a0.z), og = sigf(a0.w);
      c0 = fg * c0 + ig * gg;
      hx[ul][b] = og * tanhf(c0);
    }
    if (t >= 1) {  // layer1 activation
      float ig = sigf(a1.x), fg = sigf(a1.y), gg = tanhf(a1.z), og = sigf(a1.w);
      c1 = fg * c1 + ig * gg;
      hx[2 + ul][b] = og * tanhf(c1);
    }
    __syncthreads();
    if (tid < 128) {  // pack both units -> one dword per (buffer, b)
      if (t < 256) hp0[(t + 1) & 1][blk * 128 + b] = packh(hx[0][b], hx[1][b]);
      if (t >= 1) hp1[t & 1][blk * 128 + b] = packh(hx[2][b], hx[3][b]);
    }
    gridbar(cnt, gen);
  }
  // final enc states: h0 in hp0[0], h1 in hp1[0]; c0,c1 in registers.

  // ================= decoder: 3 rounds per step ============================
  for (int s = 0; s < 256; ++s) {
    {  // R_A: dec layer0 (input = previous fc output, 6-dim)
      float4 a = make_float4(bd0[0], bd0[1], bd0[2], bd0[3]);
      float xv[6];
#pragma unroll
      for (int i = 0; i < 6; ++i) xv[i] = outp[i * 128 + b];
      dot_one(a, wl + (3 * 2 + ul) * 2048, hp0[s & 1] + b);
#pragma unroll
      for (int i = 0; i < 6; ++i) {
        a.x = fmaf(wx0d[i], xv[i], a.x);
        a.y = fmaf(wx0d[6 + i], xv[i], a.y);
        a.z = fmaf(wx0d[12 + i], xv[i], a.z);
        a.w = fmaf(wx0d[18 + i], xv[i], a.w);
      }
      float ig = sigf(a.x), fg = sigf(a.y), gg = tanhf(a.z), og = sigf(a.w);
      c0 = fg * c0 + ig * gg;
      hx[ul][b] = og * tanhf(c0);
      __syncthreads();
      if (tid < 128) hp0[(s + 1) & 1][blk * 128 + b] = packh(hx[0][b], hx[1][b]);
    }
    gridbar(cnt, gen);
    {  // R_B: dec layer1 (inputs: dh0[s] just written, dh1[s-1])
      float4 a = make_float4(bd1[0], bd1[1], bd1[2], bd1[3]);
      dot_one(a, wl + (4 * 2 + ul) * 2048, hp0[(s + 1) & 1] + b);
      dot_one(a, wl + (5 * 2 + ul) * 2048, hp1[s & 1] + b);
      float ig = sigf(a.x), fg = sigf(a.y), gg = tanhf(a.z), og = sigf(a.w);
      c1 = fg * c1 + ig * gg;
      hx[ul][b] = og * tanhf(c1);
      __syncthreads();
      if (tid < 128) hp1[(s + 1) & 1][blk * 128 + b] = packh(hx[0][b], hx[1][b]);
    }
    gridbar(cnt, gen);
    {  // R_C: fc head, 3 outputs per block, 64 lanes each, shuffle-reduce
      int q = tid >> 6, l = tid & 63;
      if (q < 3) {
        int o = blk * 3 + q;  // 0..767
        int j = o >> 7, bb = o & 127;
        const unsigned *hc = hp1[(s + 1) & 1] + bb;
        const float2 *fw = (const float2 *)(p.fcW + j * 512);
        float acc = 0.f;
#pragma unroll
        for (int r = 0; r < 4; ++r) {
          int k2 = l + r * 64;
          unsigned d = hc[k2 * 128];
          float2 hf = __half22float2(*(const __half2 *)&d);
          float2 wv = fw[k2];
          acc = fmaf(wv.x, hf.x, acc);
          acc = fmaf(wv.y, hf.y, acc);
        }
#pragma unroll
        for (int off = 32; off; off >>= 1) acc += __shfl_down(acc, off, 64);
        if (l == 0) {
          acc += p.fcb[j];
          outp[j * 128 + bb] = acc;                    // next decoder input
          p.out[((size_t)bb * 256 + s) * 6 + j] = acc; // final output (fp32)
        }
      }
    }
    gridbar(cnt, gen);
  }
}

extern "C" void kernel_launch(void *const *d_in, const int *in_sizes, int n_in,
                              void *d_out, int out_size, void *d_ws, size_t ws_size,
                              hipStream_t stream) {
  (void)in_sizes; (void)n_in; (void)out_size; (void)ws_size;
  P19 p;
  p.src = (const float *)d_in[0];
  p.eWih0 = (const float *)d_in[1];  p.eWhh0 = (const float *)d_in[2];
  p.ebih0 = (const float *)d_in[3];  p.ebhh0 = (const float *)d_in[4];
  p.eWih1 = (const float *)d_in[5];  p.eWhh1 = (const float *)d_in[6];
  p.ebih1 = (const float *)d_in[7];  p.ebhh1 = (const float *)d_in[8];
  p.dWih0 = (const float *)d_in[9];  p.dWhh0 = (const float *)d_in[10];
  p.dbih0 = (const float *)d_in[11]; p.dbhh0 = (const float *)d_in[12];
  p.dWih1 = (const float *)d_in[13]; p.dWhh1 = (const float *)d_in[14];
  p.dbih1 = (const float *)d_in[15]; p.dbhh1 = (const float *)d_in[16];
  p.fcW = (const float *)d_in[17];   p.fcb = (const float *)d_in[18];
  p.out = (float *)d_out;
  p.ws = (float *)d_ws;

  // zero barrier words + the 4 packed-h parity buffers (outp written by the
  // kernel's init phase before first use). Graph-capture-legal.
  hipMemsetAsync(d_ws, 0, (size_t)(64 + 4 * 32768) * sizeof(float), stream);
  seq2seq_kernel<<<dim3(256), dim3(256), 0, stream>>>(p);
}

// Round 5
// 24278.580 us; speedup vs baseline: 3.5654x; 1.7868x over previous
//
#include <hip/hip_runtime.h>
#include <hip/hip_fp16.h>

// ---------------- parameters (all inputs fp32; output fp32) ----------------
struct P19 {
  const float *src;
  const float *eWih0, *eWhh0, *ebih0, *ebhh0;
  const float *eWih1, *eWhh1, *ebih1, *ebhh1;
  const float *dWih0, *dWhh0, *dbih0, *dbhh0;
  const float *dWih1, *dWhh1, *dbih1, *dbhh1;
  const float *fcW, *fcb;
  float *out;
  float *ws;
};

__device__ __forceinline__ float sigf(float x) {
  return 1.f / (1.f + __expf(-x));
}

__device__ __forceinline__ unsigned packh(float a, float b2) {
  __half2 h2 = __floats2half2_rn(a, b2);
  return *(const unsigned *)&h2;
}

// -------- distributed-flag grid barrier: NO serialized RMW chain ----------
// arrival: each block stores gen to its own 128B-spaced flag (parallel).
// block 0: 256 threads poll the 256 flags in parallel, then one 'go' store.
// others: read-poll 'go' (reads to one line don't bounce ownership).
// All 256 blocks resident (114KB LDS -> 1 block/CU, grid == CU count).
__device__ __forceinline__ void gridbar(unsigned *flags, unsigned *go,
                                        unsigned gen, int tid, int blk) {
  __syncthreads();
  if (tid == 0) {
    __threadfence();  // release: flush our h writes to L3
    __hip_atomic_store(flags + blk * 32, gen, __ATOMIC_RELEASE, __HIP_MEMORY_SCOPE_AGENT);
  }
  if (blk == 0) {
    unsigned *f = flags + tid * 32;
    int guard = 0;
    while (__hip_atomic_load(f, __ATOMIC_RELAXED, __HIP_MEMORY_SCOPE_AGENT) < gen) {
      __builtin_amdgcn_s_sleep(1);
      if (++guard > (1 << 16)) break;  // safety: never deadlock the bench
    }
    __syncthreads();
    if (tid == 0)
      __hip_atomic_store(go, gen, __ATOMIC_RELEASE, __HIP_MEMORY_SCOPE_AGENT);
  } else if (tid == 0) {
    int guard = 0;
    while (__hip_atomic_load(go, __ATOMIC_RELAXED, __HIP_MEMORY_SCOPE_AGENT) < gen) {
      __builtin_amdgcn_s_sleep(1);
      if (++guard > (1 << 16)) break;
    }
  }
  if (tid == 0) __threadfence();  // acquire: invalidate L1/L2 before reading h
  __syncthreads();
}

// ---- pipelined dots over packed-fp16 h (256 dwords = 512 k) ----
// w layout per k2: 8 floats = [4 gates @ k=2k2][4 gates @ k=2k2+1]
#define DBODY(ACC, WP)                                                \
  {                                                                   \
    const float4 *W = (const float4 *)((WP) + k2 * 8);                \
    float4 we = W[0], wo = W[1];                                      \
    ACC.x = fmaf(we.x, hf.x, ACC.x); ACC.y = fmaf(we.y, hf.x, ACC.y); \
    ACC.z = fmaf(we.z, hf.x, ACC.z); ACC.w = fmaf(we.w, hf.x, ACC.w); \
    ACC.x = fmaf(wo.x, hf.y, ACC.x); ACC.y = fmaf(wo.y, hf.y, ACC.y); \
    ACC.z = fmaf(wo.z, hf.y, ACC.z); ACC.w = fmaf(wo.w, hf.y, ACC.w); \
  }

__device__ __forceinline__ void dot_one(float4 &A0, const float *__restrict__ w0,
                                        const unsigned *__restrict__ hp) {
  unsigned bufa[32], bufb[32];
#pragma unroll
  for (int c = 0; c < 32; ++c) bufa[c] = hp[c * 128];
  for (int j = 0; j < 8; j += 2) {
    int jn = j + 1, jn2 = (j + 2) & 7;  // wrap: redundant reload, harmless
#pragma unroll
    for (int c = 0; c < 32; ++c) bufb[c] = hp[(jn * 32 + c) * 128];
#pragma unroll
    for (int c = 0; c < 32; ++c) {
      int k2 = j * 32 + c;
      unsigned d = bufa[c];
      float2 hf = __half22float2(*(const __half2 *)&d);
      DBODY(A0, w0)
    }
#pragma unroll
    for (int c = 0; c < 32; ++c) bufa[c] = hp[(jn2 * 32 + c) * 128];
#pragma unroll
    for (int c = 0; c < 32; ++c) {
      int k2 = jn * 32 + c;
      unsigned d = bufb[c];
      float2 hf = __half22float2(*(const __half2 *)&d);
      DBODY(A0, w0)
    }
  }
}

// shared h loads feeding two weight sets (enc layer0 + layer1 read same h0)
__device__ __forceinline__ void dot_two(float4 &A0, float4 &A1,
                                        const float *__restrict__ w0,
                                        const float *__restrict__ w1,
                                        const unsigned *__restrict__ hp) {
  unsigned bufa[32], bufb[32];
#pragma unroll
  for (int c = 0; c < 32; ++c) bufa[c] = hp[c * 128];
  for (int j = 0; j < 8; j += 2) {
    int jn = j + 1, jn2 = (j + 2) & 7;
#pragma unroll
    for (int c = 0; c < 32; ++c) bufb[c] = hp[(jn * 32 + c) * 128];
#pragma unroll
    for (int c = 0; c < 32; ++c) {
      int k2 = j * 32 + c;
      unsigned d = bufa[c];
      float2 hf = __half22float2(*(const __half2 *)&d);
      DBODY(A0, w0)
      DBODY(A1, w1)
    }
#pragma unroll
    for (int c = 0; c < 32; ++c) bufa[c] = hp[(jn2 * 32 + c) * 128];
#pragma unroll
    for (int c = 0; c < 32; ++c) {
      int k2 = jn * 32 + c;
      unsigned d = bufb[c];
      float2 hf = __half22float2(*(const __half2 *)&d);
      DBODY(A0, w0)
      DBODY(A1, w1)
    }
  }
}

__global__ __launch_bounds__(256, 1) void seq2seq_kernel(P19 p) {
  const int tid = threadIdx.x;
  const int blk = blockIdx.x;
  const int b = tid & 127;     // batch
  const int ul = tid >> 7;     // unit-local (0..1)
  const int u = blk * 2 + ul;  // hidden unit 0..511

  float *ws = p.ws;
  unsigned *flags = (unsigned *)ws;        // 256 flags, 32-dword spacing
  unsigned *go = (unsigned *)ws + 8192;    // own cache line
  unsigned *hp0[2] = {(unsigned *)(ws + 8256), (unsigned *)(ws + 8256 + 32768)};
  unsigned *hp1[2] = {(unsigned *)(ws + 8256 + 65536), (unsigned *)(ws + 8256 + 98304)};
  float *outp = ws + 8256 + 131072;  // decoder seed input [j][b] : 6*128 fp32

  // LDS: 7 matrices x 2 units x 512 k x 4 gates fp32 = 112 KiB (+2KB exchange)
  __shared__ __align__(16) float wl[28672];
  __shared__ float hx[4][128];

  {  // ---- stage big-weight slices into LDS (once) ----
    const float *mats[6] = {p.eWhh0, p.eWih1, p.eWhh1, p.dWhh0, p.dWih1, p.dWhh1};
    for (int m = 0; m < 6; ++m)
      for (int uu = 0; uu < 2; ++uu) {
        int unit = blk * 2 + uu;
        for (int g = 0; g < 4; ++g) {
          const float *row = mats[m] + (size_t)(g * 512 + unit) * 512;
          float *dst = wl + (m * 2 + uu) * 2048 + g;
          for (int k = tid; k < 512; k += 256) dst[k * 4] = row[k];
        }
      }
  }

  // ---- per-thread small weights & fused biases (registers) ----
  float wx0e[24], wx0d[24], be0[4], be1[4], bd0[4], bd1[4], bd0pp[4];
#pragma unroll
  for (int g = 0; g < 4; ++g) {
    int r = g * 512 + u;
#pragma unroll
    for (int i = 0; i < 6; ++i) {
      wx0e[g * 6 + i] = p.eWih0[r * 6 + i];
      wx0d[g * 6 + i] = p.dWih0[r * 6 + i];
    }
    be0[g] = p.ebih0[r] + p.ebhh0[r];
    be1[g] = p.ebih1[r] + p.ebhh1[r];
    bd0[g] = p.dbih0[r] + p.dbhh0[r];
    bd1[g] = p.dbih1[r] + p.dbhh1[r];
  }
  // b'' = bd0 + dec_Wih0 @ fcb  (for fused decoder layer0, s>=1)
#pragma unroll
  for (int g = 0; g < 4; ++g) {
    float v = bd0[g];
#pragma unroll
    for (int i = 0; i < 6; ++i) v = fmaf(wx0d[g * 6 + i], p.fcb[i], v);
    bd0pp[g] = v;
  }

  // ---- W' = dec_Wih0 @ fcW (2048x512), this block's 2-unit slice -> LDS m=6
  // thread (ul,b) computes k = 4b..4b+3 for its unit's 4 gate rows
  for (int kk = 0; kk < 4; ++kk) {
    int k = b * 4 + kk;
    float f6[6];
#pragma unroll
    for (int i = 0; i < 6; ++i) f6[i] = p.fcW[i * 512 + k];
#pragma unroll
    for (int g = 0; g < 4; ++g) {
      float v = 0.f;
#pragma unroll
      for (int i = 0; i < 6; ++i) v = fmaf(wx0d[g * 6 + i], f6[i], v);
      wl[(12 + ul) * 2048 + k * 4 + g] = v;
    }
  }

  // ---- init: seed decoder input = src[:,255,:] ----
  {
    int g0 = blk * 256 + tid;
    if (g0 < 768) {
      int bb = g0 & 127, i = g0 >> 7;
      outp[i * 128 + bb] = p.src[((size_t)bb * 256 + 255) * 6 + i];
    }
  }
  float c0 = 0.f, c1 = 0.f;  // cell states live in registers forever
  unsigned gen = 0;
  __syncthreads();  // LDS staging visible block-locally before first dot

  // ================= encoder: layer0 & layer1 pipelined (lag 1) ============
  for (int t = 0; t <= 256; ++t) {
    float4 a0 = make_float4(be0[0], be0[1], be0[2], be0[3]);
    float4 a1 = make_float4(be1[0], be1[1], be1[2], be1[3]);
    float xv[6];
    if (t < 256) {
      const float *xr = p.src + ((size_t)b * 256 + t) * 6;
#pragma unroll
      for (int i = 0; i < 6; ++i) xv[i] = xr[i];
    }
    const unsigned *hpA = hp0[t & 1] + b;
    if (t == 0) {
      dot_one(a0, wl + (0 * 2 + ul) * 2048, hpA);
    } else if (t < 256) {
      dot_two(a0, a1, wl + (0 * 2 + ul) * 2048, wl + (1 * 2 + ul) * 2048, hpA);
    } else {
      dot_one(a1, wl + (1 * 2 + ul) * 2048, hpA);
    }
    if (t >= 1) dot_one(a1, wl + (2 * 2 + ul) * 2048, hp1[(t + 1) & 1] + b);

    if (t < 256) {  // layer0 activation
#pragma unroll
      for (int i = 0; i < 6; ++i) {
        a0.x = fmaf(wx0e[i], xv[i], a0.x);
        a0.y = fmaf(wx0e[6 + i], xv[i], a0.y);
        a0.z = fmaf(wx0e[12 + i], xv[i], a0.z);
        a0.w = fmaf(wx0e[18 + i], xv[i], a0.w);
      }
      float ig = sigf(a0.x), fg = sigf(a0.y), gg = tanhf(a0.z), og = sigf(a0.w);
      c0 = fg * c0 + ig * gg;
      hx[ul][b] = og * tanhf(c0);
    }
    if (t >= 1) {  // layer1 activation
      float ig = sigf(a1.x), fg = sigf(a1.y), gg = tanhf(a1.z), og = sigf(a1.w);
      c1 = fg * c1 + ig * gg;
      hx[2 + ul][b] = og * tanhf(c1);
    }
    __syncthreads();
    if (tid < 128) {
      if (t < 256) hp0[(t + 1) & 1][blk * 128 + b] = packh(hx[0][b], hx[1][b]);
      if (t >= 1) hp1[t & 1][blk * 128 + b] = packh(hx[2][b], hx[3][b]);
    }
    gridbar(flags, go, ++gen, tid, blk);
  }
  // final enc states: h0 in hp0[0], h1 in hp1[0]; c0,c1 in registers.

  // ========== decoder: 2 rounds/step (fc folded into layer0 via W') ========
  for (int s = 0; s < 256; ++s) {
    {  // R_A: dec layer0.  s=0: x-input path; s>=1: + W' @ h1[s-1]
      float4 a;
      if (s == 0) {
        a = make_float4(bd0[0], bd0[1], bd0[2], bd0[3]);
#pragma unroll
        for (int i = 0; i < 6; ++i) {
          float xvv = outp[i * 128 + b];
          a.x = fmaf(wx0d[i], xvv, a.x);
          a.y = fmaf(wx0d[6 + i], xvv, a.y);
          a.z = fmaf(wx0d[12 + i], xvv, a.z);
          a.w = fmaf(wx0d[18 + i], xvv, a.w);
        }
        dot_one(a, wl + (3 * 2 + ul) * 2048, hp0[0] + b);
      } else {
        a = make_float4(bd0pp[0], bd0pp[1], bd0pp[2], bd0pp[3]);
        dot_one(a, wl + (3 * 2 + ul) * 2048, hp0[s & 1] + b);
        dot_one(a, wl + (12 + ul) * 2048, hp1[s & 1] + b);
      }
      float ig = sigf(a.x), fg = sigf(a.y), gg = tanhf(a.z), og = sigf(a.w);
      c0 = fg * c0 + ig * gg;
      hx[ul][b] = og * tanhf(c0);

      if (s >= 1) {  // emit out[s-1] = fcW @ h1[s-1] + fcb (write-only)
        int q = tid >> 6, l = tid & 63;
        if (q < 3) {
          int o = blk * 3 + q, j = o >> 7, bb = o & 127;
          const unsigned *hc = hp1[s & 1] + bb;
          const float2 *fw = (const float2 *)(p.fcW + j * 512);
          float acc = 0.f;
#pragma unroll
          for (int r = 0; r < 4; ++r) {
            int k2 = l + r * 64;
            unsigned d = hc[k2 * 128];
            float2 hf = __half22float2(*(const __half2 *)&d);
            float2 wv = fw[k2];
            acc = fmaf(wv.x, hf.x, acc);
            acc = fmaf(wv.y, hf.y, acc);
          }
#pragma unroll
          for (int off = 32; off; off >>= 1) acc += __shfl_down(acc, off, 64);
          if (l == 0) p.out[((size_t)bb * 256 + (s - 1)) * 6 + j] = acc + p.fcb[j];
        }
      }
      __syncthreads();
      if (tid < 128) hp0[(s + 1) & 1][blk * 128 + b] = packh(hx[0][b], hx[1][b]);
    }
    gridbar(flags, go, ++gen, tid, blk);
    {  // R_B: dec layer1 (inputs: dh0[s] just written, dh1[s-1])
      float4 a = make_float4(bd1[0], bd1[1], bd1[2], bd1[3]);
      dot_one(a, wl + (4 * 2 + ul) * 2048, hp0[(s + 1) & 1] + b);
      dot_one(a, wl + (5 * 2 + ul) * 2048, hp1[s & 1] + b);
      float ig = sigf(a.x), fg = sigf(a.y), gg = tanhf(a.z), og = sigf(a.w);
      c1 = fg * c1 + ig * gg;
      hx[ul][b] = og * tanhf(c1);
      __syncthreads();
      if (tid < 128) hp1[(s + 1) & 1][blk * 128 + b] = packh(hx[0][b], hx[1][b]);
    }
    gridbar(flags, go, ++gen, tid, blk);
  }
  {  // tail: out[255] = fcW @ h1[255] + fcb   (h1[255] is in hp1[0])
    int q = tid >> 6, l = tid & 63;
    if (q < 3) {
      int o = blk * 3 + q, j = o >> 7, bb = o & 127;
      const unsigned *hc = hp1[0] + bb;
      const float2 *fw = (const float2 *)(p.fcW + j * 512);
      float acc = 0.f;
#pragma unroll
      for (int r = 0; r < 4; ++r) {
        int k2 = l + r * 64;
        unsigned d = hc[k2 * 128];
        float2 hf = __half22float2(*(const __half2 *)&d);
        float2 wv = fw[k2];
        acc = fmaf(wv.x, hf.x, acc);
        acc = fmaf(wv.y, hf.y, acc);
      }
#pragma unroll
      for (int off = 32; off; off >>= 1) acc += __shfl_down(acc, off, 64);
      if (l == 0) p.out[((size_t)bb * 256 + 255) * 6 + j] = acc + p.fcb[j];
    }
  }
}

extern "C" void kernel_launch(void *const *d_in, const int *in_sizes, int n_in,
                              void *d_out, int out_size, void *d_ws, size_t ws_size,
                              hipStream_t stream) {
  (void)in_sizes; (void)n_in; (void)out_size; (void)ws_size;
  P19 p;
  p.src = (const float *)d_in[0];
  p.eWih0 = (const float *)d_in[1];  p.eWhh0 = (const float *)d_in[2];
  p.ebih0 = (const float *)d_in[3];  p.ebhh0 = (const float *)d_in[4];
  p.eWih1 = (const float *)d_in[5];  p.eWhh1 = (const float *)d_in[6];
  p.ebih1 = (const float *)d_in[7];  p.ebhh1 = (const float *)d_in[8];
  p.dWih0 = (const float *)d_in[9];  p.dWhh0 = (const float *)d_in[10];
  p.dbih0 = (const float *)d_in[11]; p.dbhh0 = (const float *)d_in[12];
  p.dWih1 = (const float *)d_in[13]; p.dWhh1 = (const float *)d_in[14];
  p.dbih1 = (const float *)d_in[15]; p.dbhh1 = (const float *)d_in[16];
  p.fcW = (const float *)d_in[17];   p.fcb = (const float *)d_in[18];
  p.out = (float *)d_out;
  p.ws = (float *)d_ws;

  // zero flags + go + 4 packed-h parity buffers (outp written by kernel init)
  hipMemsetAsync(d_ws, 0, (size_t)(8256 + 4 * 32768) * sizeof(float), stream);
  seq2seq_kernel<<<dim3(256), dim3(256), 0, stream>>>(p);
}

// Round 6
// 20674.335 us; speedup vs baseline: 4.1870x; 1.1743x over previous
//
#include <hip/hip_runtime.h>
#include <hip/hip_fp16.h>

// ---------------- parameters (all inputs fp32; output fp32) ----------------
struct P19 {
  const float *src;
  const float *eWih0, *eWhh0, *ebih0, *ebhh0;
  const float *eWih1, *eWhh1, *ebih1, *ebhh1;
  const float *dWih0, *dWhh0, *dbih0, *dbhh0;
  const float *dWih1, *dWhh1, *dbih1, *dbhh1;
  const float *fcW, *fcb;
  float *out;
  float *ws;
};

typedef _Float16 h2_t __attribute__((ext_vector_type(2)));

__device__ __forceinline__ float sigf(float x) {
  return 1.f / (1.f + __expf(-x));
}

__device__ __forceinline__ unsigned packh(float a, float b2) {
  __half2 h2 = __floats2half2_rn(a, b2);
  return *(const unsigned *)&h2;
}

// fp16x2 dot with fp32 accumulate: v_dot2_f32_f16
__device__ __forceinline__ float dot2(unsigned h, unsigned w, float acc) {
#if __has_builtin(__builtin_amdgcn_fdot2)
  return __builtin_amdgcn_fdot2(*(h2_t *)&h, *(h2_t *)&w, acc, false);
#else
  float2 hf = __half22float2(*(const __half2 *)&h);
  float2 wf = __half22float2(*(const __half2 *)&w);
  return fmaf(hf.x, wf.x, fmaf(hf.y, wf.y, acc));
#endif
}

// ---- symmetric distributed-flag grid barrier (one propagation hop) -------
// each block stores gen to its own 128B-spaced flag; every block's first 256
// threads poll all 256 flags in parallel. 82KB LDS -> 1 block/CU guaranteed.
__device__ __forceinline__ void gridbar(unsigned *flags, unsigned gen,
                                        int tid, int blk) {
  __syncthreads();
  if (tid == 0) {
    __threadfence();  // release: flush h writes toward coherence point
    __hip_atomic_store(flags + blk * 32, gen, __ATOMIC_RELEASE, __HIP_MEMORY_SCOPE_AGENT);
  }
  if (tid < 256) {
    unsigned *f = flags + tid * 32;
    int guard = 0;
    while (__hip_atomic_load(f, __ATOMIC_RELAXED, __HIP_MEMORY_SCOPE_AGENT) < gen) {
      __builtin_amdgcn_s_sleep(4);
      if (++guard > (1 << 16)) break;  // safety: never deadlock the bench
    }
  }
  __syncthreads();
  if (tid == 0) __threadfence();  // acquire: invalidate before reading h
  __syncthreads();
}

// ---- half-dot over this thread's 128-k2 range (k-split across kh) --------
// weights: uint4 per k2 = 4 gates x half2; h: packed fp16 [k2][b] dwords
__device__ __forceinline__ void dotk(float4 &A, const uint4 *__restrict__ wm,
                                     const unsigned *__restrict__ hp, int kh) {
  const unsigned *hpp = hp + kh * 16384;  // + (kh*128 k2) * 128
  const uint4 *wp = wm + kh * 128;
  unsigned ca[16], cb[16];
#pragma unroll
  for (int c = 0; c < 16; ++c) ca[c] = hpp[c * 128];
  for (int j = 0; j < 8; j += 2) {
#pragma unroll
    for (int c = 0; c < 16; ++c) cb[c] = hpp[((j + 1) * 16 + c) * 128];
#pragma unroll
    for (int c = 0; c < 16; ++c) {
      uint4 w = wp[j * 16 + c];
      A.x = dot2(ca[c], w.x, A.x);
      A.y = dot2(ca[c], w.y, A.y);
      A.z = dot2(ca[c], w.z, A.z);
      A.w = dot2(ca[c], w.w, A.w);
    }
#pragma unroll
    for (int c = 0; c < 16; ++c) ca[c] = hpp[((((j + 2) & 7)) * 16 + c) * 128];
#pragma unroll
    for (int c = 0; c < 16; ++c) {
      uint4 w = wp[(j + 1) * 16 + c];
      A.x = dot2(cb[c], w.x, A.x);
      A.y = dot2(cb[c], w.y, A.y);
      A.z = dot2(cb[c], w.z, A.z);
      A.w = dot2(cb[c], w.w, A.w);
    }
  }
}

// two weight sets sharing one h stream (enc layer0 + layer1 read same h0)
__device__ __forceinline__ void dotk2(float4 &A0, float4 &A1,
                                      const uint4 *__restrict__ w0,
                                      const uint4 *__restrict__ w1,
                                      const unsigned *__restrict__ hp, int kh) {
  const unsigned *hpp = hp + kh * 16384;
  const uint4 *p0 = w0 + kh * 128, *p1 = w1 + kh * 128;
  unsigned ca[16], cb[16];
#pragma unroll
  for (int c = 0; c < 16; ++c) ca[c] = hpp[c * 128];
  for (int j = 0; j < 8; j += 2) {
#pragma unroll
    for (int c = 0; c < 16; ++c) cb[c] = hpp[((j + 1) * 16 + c) * 128];
#pragma unroll
    for (int c = 0; c < 16; ++c) {
      int idx = j * 16 + c;
      uint4 wa = p0[idx], wb = p1[idx];
      A0.x = dot2(ca[c], wa.x, A0.x); A0.y = dot2(ca[c], wa.y, A0.y);
      A0.z = dot2(ca[c], wa.z, A0.z); A0.w = dot2(ca[c], wa.w, A0.w);
      A1.x = dot2(ca[c], wb.x, A1.x); A1.y = dot2(ca[c], wb.y, A1.y);
      A1.z = dot2(ca[c], wb.z, A1.z); A1.w = dot2(ca[c], wb.w, A1.w);
    }
#pragma unroll
    for (int c = 0; c < 16; ++c) ca[c] = hpp[((((j + 2) & 7)) * 16 + c) * 128];
#pragma unroll
    for (int c = 0; c < 16; ++c) {
      int idx = (j + 1) * 16 + c;
      uint4 wa = p0[idx], wb = p1[idx];
      A0.x = dot2(cb[c], wa.x, A0.x); A0.y = dot2(cb[c], wa.y, A0.y);
      A0.z = dot2(cb[c], wa.z, A0.z); A0.w = dot2(cb[c], wa.w, A0.w);
      A1.x = dot2(cb[c], wb.x, A1.x); A1.y = dot2(cb[c], wb.y, A1.y);
      A1.z = dot2(cb[c], wb.z, A1.z); A1.w = dot2(cb[c], wb.w, A1.w);
    }
  }
}

__global__ __launch_bounds__(512, 1) void seq2seq_kernel(P19 p) {
  const int tid = threadIdx.x;
  const int blk = blockIdx.x;
  const int b = tid & 127;          // batch
  const int ul = (tid >> 7) & 1;    // unit-local (0..1)
  const int kh = tid >> 8;          // k-half (0..1)
  const int u = blk * 2 + ul;       // hidden unit 0..511

  float *ws = p.ws;
  unsigned *flags = (unsigned *)ws;  // 256 flags, 32-dword spacing
  unsigned *hp0[2] = {(unsigned *)(ws + 8256), (unsigned *)(ws + 8256 + 32768)};
  unsigned *hp1[2] = {(unsigned *)(ws + 8256 + 65536), (unsigned *)(ws + 8256 + 98304)};
  float *outp = ws + 8256 + 131072;  // decoder seed input [j][b] : 6*128

  // LDS: 7 matrices x 2 units x 256 k2 x (4 gates half2 = 16B) = 56 KiB
  __shared__ __align__(16) uint4 wl4[3584];
  __shared__ float4 redux[2][2][128];  // 8 KB: cross-kh partial-dot exchange
  __shared__ float hx[4][128];         // 2 KB: cross-ul h exchange
  __shared__ float pad[3600];          // 14 KB: pin LDS >80KB -> 1 block/CU
  unsigned *wl1 = (unsigned *)wl4;

  {  // ---- stage big-weight slices into LDS as half2 (once) ----
    const float *mats[6] = {p.eWhh0, p.eWih1, p.eWhh1, p.dWhh0, p.dWih1, p.dWhh1};
    for (int m = 0; m < 6; ++m)
      for (int uu = 0; uu < 2; ++uu) {
        int unit = blk * 2 + uu;
        for (int e = tid; e < 1024; e += 512) {
          int g = e & 3, k2 = e >> 2;
          const float *row = mats[m] + (size_t)(g * 512 + unit) * 512;
          wl1[((m * 2 + uu) * 256 + k2) * 4 + g] = packh(row[2 * k2], row[2 * k2 + 1]);
        }
      }
    // W' = dec_Wih0 @ fcW (fused fc->dec-layer0), slice -> matrix slot 6
    for (int e = tid; e < 2048; e += 512) {
      int uu = e >> 10, rem = e & 1023, g = rem & 3, k2 = rem >> 2;
      int unit = blk * 2 + uu;
      const float *wr = p.dWih0 + (size_t)(g * 512 + unit) * 6;
      float v0 = 0.f, v1 = 0.f;
#pragma unroll
      for (int i = 0; i < 6; ++i) {
        v0 = fmaf(wr[i], p.fcW[i * 512 + 2 * k2], v0);
        v1 = fmaf(wr[i], p.fcW[i * 512 + 2 * k2 + 1], v1);
      }
      wl1[((12 + uu) * 256 + k2) * 4 + g] = packh(v0, v1);
    }
    for (int i = tid; i < 3600; i += 512) pad[i] = 0.f;  // keep pad live
  }

  // ---- per-thread small weights & fused biases (used by kh==0 only) ----
  float wx0e[24], wx0d[24], be0[4], be1[4], bd0[4], bd1[4], bd0pp[4];
#pragma unroll
  for (int g = 0; g < 4; ++g) {
    int r = g * 512 + u;
#pragma unroll
    for (int i = 0; i < 6; ++i) {
      wx0e[g * 6 + i] = p.eWih0[r * 6 + i];
      wx0d[g * 6 + i] = p.dWih0[r * 6 + i];
    }
    be0[g] = p.ebih0[r] + p.ebhh0[r];
    be1[g] = p.ebih1[r] + p.ebhh1[r];
    bd0[g] = p.dbih0[r] + p.dbhh0[r];
    bd1[g] = p.dbih1[r] + p.dbhh1[r];
  }
#pragma unroll
  for (int g = 0; g < 4; ++g) {  // b'' = bd0 + dec_Wih0 @ fcb
    float v = bd0[g];
#pragma unroll
    for (int i = 0; i < 6; ++i) v = fmaf(wx0d[g * 6 + i], p.fcb[i], v);
    bd0pp[g] = v;
  }

  // ---- init: seed decoder input = src[:,255,:] ----
  {
    int g0 = blk * 512 + tid;
    if (g0 < 768) {
      int bb = g0 & 127, i = g0 >> 7;
      outp[i * 128 + bb] = p.src[((size_t)bb * 256 + 255) * 6 + i];
    }
  }
  float c0 = 0.f, c1 = 0.f;  // cell states (kh==0 threads) live in registers
  unsigned gen = 0;
  __syncthreads();  // LDS staging visible block-locally

#define WLM(m) (wl4 + ((m) * 2 + ul) * 256)

  // ================= encoder: layer0 & layer1 pipelined (lag 1) ============
  for (int t = 0; t <= 256; ++t) {
    float4 a0 = make_float4(0.f, 0.f, 0.f, 0.f);
    float4 a1 = make_float4(0.f, 0.f, 0.f, 0.f);
    const unsigned *hpA = hp0[t & 1] + b;
    if (t == 0) {
      dotk(a0, WLM(0), hpA, kh);
    } else if (t < 256) {
      dotk2(a0, a1, WLM(0), WLM(1), hpA, kh);
    } else {
      dotk(a1, WLM(1), hpA, kh);
    }
    if (t >= 1) dotk(a1, WLM(2), hp1[(t + 1) & 1] + b, kh);

    if (kh == 1) {
      redux[0][ul][b] = a0;
      redux[1][ul][b] = a1;
    }
    __syncthreads();
    if (kh == 0) {
      float4 r0 = redux[0][ul][b], r1 = redux[1][ul][b];
      a0.x += r0.x; a0.y += r0.y; a0.z += r0.z; a0.w += r0.w;
      a1.x += r1.x; a1.y += r1.y; a1.z += r1.z; a1.w += r1.w;
      if (t < 256) {  // layer0 activation
        const float *xr = p.src + ((size_t)b * 256 + t) * 6;
        a0.x += be0[0]; a0.y += be0[1]; a0.z += be0[2]; a0.w += be0[3];
#pragma unroll
        for (int i = 0; i < 6; ++i) {
          float xv = xr[i];
          a0.x = fmaf(wx0e[i], xv, a0.x);
          a0.y = fmaf(wx0e[6 + i], xv, a0.y);
          a0.z = fmaf(wx0e[12 + i], xv, a0.z);
          a0.w = fmaf(wx0e[18 + i], xv, a0.w);
        }
        float ig = sigf(a0.x), fg = sigf(a0.y), gg = tanhf(a0.z), og = sigf(a0.w);
        c0 = fg * c0 + ig * gg;
        hx[ul][b] = og * tanhf(c0);
      }
      if (t >= 1) {  // layer1 activation
        a1.x += be1[0]; a1.y += be1[1]; a1.z += be1[2]; a1.w += be1[3];
        float ig = sigf(a1.x), fg = sigf(a1.y), gg = tanhf(a1.z), og = sigf(a1.w);
        c1 = fg * c1 + ig * gg;
        hx[2 + ul][b] = og * tanhf(c1);
      }
    }
    __syncthreads();
    if (tid < 128) {
      if (t < 256) hp0[(t + 1) & 1][blk * 128 + b] = packh(hx[0][b], hx[1][b]);
      if (t >= 1) hp1[t & 1][blk * 128 + b] = packh(hx[2][b], hx[3][b]);
    }
    gridbar(flags, ++gen, tid, blk);
  }
  // final enc states: h0 in hp0[0], h1 in hp1[0]; c0,c1 in registers.

  // ========== decoder: 2 rounds/step (fc folded into layer0 via W') ========
  for (int s = 0; s < 256; ++s) {
    {  // R_A: dec layer0
      float4 a = make_float4(0.f, 0.f, 0.f, 0.f);
      dotk(a, WLM(3), hp0[s & 1] + b, kh);
      if (s >= 1) dotk(a, wl4 + (12 + ul) * 256, hp1[s & 1] + b, kh);
      if (kh == 1) redux[0][ul][b] = a;
      __syncthreads();
      if (kh == 0) {
        float4 r0 = redux[0][ul][b];
        a.x += r0.x; a.y += r0.y; a.z += r0.z; a.w += r0.w;
        if (s == 0) {
          a.x += bd0[0]; a.y += bd0[1]; a.z += bd0[2]; a.w += bd0[3];
#pragma unroll
          for (int i = 0; i < 6; ++i) {
            float xv = outp[i * 128 + b];
            a.x = fmaf(wx0d[i], xv, a.x);
            a.y = fmaf(wx0d[6 + i], xv, a.y);
            a.z = fmaf(wx0d[12 + i], xv, a.z);
            a.w = fmaf(wx0d[18 + i], xv, a.w);
          }
        } else {
          a.x += bd0pp[0]; a.y += bd0pp[1]; a.z += bd0pp[2]; a.w += bd0pp[3];
        }
        float ig = sigf(a.x), fg = sigf(a.y), gg = tanhf(a.z), og = sigf(a.w);
        c0 = fg * c0 + ig * gg;
        hx[ul][b] = og * tanhf(c0);
        if (s >= 1) {  // emit out[s-1] = fcW @ h1[s-1] + fcb
          int q = tid >> 6, l = tid & 63;
          if (q < 3) {
            int o = blk * 3 + q, j = o >> 7, bb = o & 127;
            const unsigned *hc = hp1[s & 1] + bb;
            const float2 *fw = (const float2 *)(p.fcW + j * 512);
            float acc = 0.f;
#pragma unroll
            for (int r = 0; r < 4; ++r) {
              int k2 = l + r * 64;
              unsigned d = hc[k2 * 128];
              float2 hf = __half22float2(*(const __half2 *)&d);
              float2 wv = fw[k2];
              acc = fmaf(wv.x, hf.x, acc);
              acc = fmaf(wv.y, hf.y, acc);
            }
#pragma unroll
            for (int off = 32; off; off >>= 1) acc += __shfl_down(acc, off, 64);
            if (l == 0)
              p.out[((size_t)bb * 256 + (s - 1)) * 6 + j] = acc + p.fcb[j] + pad[j];
          }
        }
      }
      __syncthreads();
      if (tid < 128) hp0[(s + 1) & 1][blk * 128 + b] = packh(hx[0][b], hx[1][b]);
    }
    gridbar(flags, ++gen, tid, blk);
    {  // R_B: dec layer1 (inputs: dh0[s] just written, dh1[s-1])
      float4 a = make_float4(0.f, 0.f, 0.f, 0.f);
      dotk(a, WLM(4), hp0[(s + 1) & 1] + b, kh);
      dotk(a, WLM(5), hp1[s & 1] + b, kh);
      if (kh == 1) redux[0][ul][b] = a;
      __syncthreads();
      if (kh == 0) {
        float4 r0 = redux[0][ul][b];
        a.x += r0.x + bd1[0]; a.y += r0.y + bd1[1];
        a.z += r0.z + bd1[2]; a.w += r0.w + bd1[3];
        float ig = sigf(a.x), fg = sigf(a.y), gg = tanhf(a.z), og = sigf(a.w);
        c1 = fg * c1 + ig * gg;
        hx[ul][b] = og * tanhf(c1);
      }
      __syncthreads();
      if (tid < 128) hp1[(s + 1) & 1][blk * 128 + b] = packh(hx[0][b], hx[1][b]);
    }
    gridbar(flags, ++gen, tid, blk);
  }
  {  // tail: out[255] = fcW @ h1[255] + fcb   (h1[255] in hp1[0])
    int q = tid >> 6, l = tid & 63;
    if (q < 3) {
      int o = blk * 3 + q, j = o >> 7, bb = o & 127;
      const unsigned *hc = hp1[0] + bb;
      const float2 *fw = (const float2 *)(p.fcW + j * 512);
      float acc = 0.f;
#pragma unroll
      for (int r = 0; r < 4; ++r) {
        int k2 = l + r * 64;
        unsigned d = hc[k2 * 128];
        float2 hf = __half22float2(*(const __half2 *)&d);
        float2 wv = fw[k2];
        acc = fmaf(wv.x, hf.x, acc);
        acc = fmaf(wv.y, hf.y, acc);
      }
#pragma unroll
      for (int off = 32; off; off >>= 1) acc += __shfl_down(acc, off, 64);
      if (l == 0) p.out[((size_t)bb * 256 + 255) * 6 + j] = acc + p.fcb[j] + pad[j];
    }
  }
}

extern "C" void kernel_launch(void *const *d_in, const int *in_sizes, int n_in,
                              void *d_out, int out_size, void *d_ws, size_t ws_size,
                              hipStream_t stream) {
  (void)in_sizes; (void)n_in; (void)out_size; (void)ws_size;
  P19 p;
  p.src = (const float *)d_in[0];
  p.eWih0 = (const float *)d_in[1];  p.eWhh0 = (const float *)d_in[2];
  p.ebih0 = (const float *)d_in[3];  p.ebhh0 = (const float *)d_in[4];
  p.eWih1 = (const float *)d_in[5];  p.eWhh1 = (const float *)d_in[6];
  p.ebih1 = (const float *)d_in[7];  p.ebhh1 = (const float *)d_in[8];
  p.dWih0 = (const float *)d_in[9];  p.dWhh0 = (const float *)d_in[10];
  p.dbih0 = (const float *)d_in[11]; p.dbhh0 = (const float *)d_in[12];
  p.dWih1 = (const float *)d_in[13]; p.dWhh1 = (const float *)d_in[14];
  p.dbih1 = (const float *)d_in[15]; p.dbhh1 = (const float *)d_in[16];
  p.fcW = (const float *)d_in[17];   p.fcb = (const float *)d_in[18];
  p.out = (float *)d_out;
  p.ws = (float *)d_ws;

  // zero flags + 4 packed-h parity buffers (outp written by kernel init)
  hipMemsetAsync(d_ws, 0, (size_t)(8256 + 4 * 32768) * sizeof(float), stream);
  seq2seq_kernel<<<dim3(256), dim3(512), 0, stream>>>(p);
}